// Round 12
// baseline (218.797 us; speedup 1.0000x reference)
//
#include <hip/hip_runtime.h>
#include <hip/hip_fp16.h>
#include <math.h>

// ---------------------------------------------------------------------------
// GCN. CSR build = bucketed counting sort, LDS atomics only (no global
// atomics: device-scope atomic-returns run memory-side at ~23 Gops/s on
// multi-XCD CDNA4 — measured R3/R4). ebuf packed (src<<9|local) in 4 B.
// t' = dinv[row] * (row @ W) (scaled in mm epilogue) so
//   agg[d] = relu(b + dinv[d] * (sum_e t'[src_e] + t'[d]))
// colw stores ONLY src (4 B); gather inner loop is pure adds.
// NEW (R12): degree-binned node permutation (built in k_p2, LDS counting
// sort) so the 8 node-groups of a gather wave have near-equal degree ->
// no divergence waste; edge loop unrolled x4 (sentinel row N for tail).
// Fusing gather into the GEMM was tried (R10) and regressed (occupancy).
// ---------------------------------------------------------------------------

#define TPB    256
#define EBLKS  256          // pass-1 edge blocks (256 -> all CUs busy)
#define BSH    9            // 512 nodes per bucket
#define BNODES (1 << BSH)

// P1a: OFS[c*EBLKS + b] = #edges of bucket c in block b's chunk
__global__ __launch_bounds__(TPB)
void k_p1hist(const int* __restrict__ dst, int* __restrict__ OFS,
              int E, int CH, int NBC) {
    __shared__ int h[512];
    int tid = threadIdx.x, b = blockIdx.x;
    for (int i = tid; i < NBC; i += TPB) h[i] = 0;
    __syncthreads();
    int beg = b * CH, end = min(E, beg + CH);
    if (beg < end) {
        int nfull = (end - beg) & ~3;
        for (int i = beg + tid * 4; i < beg + nfull; i += TPB * 4) {
            int4 d = *(const int4*)&dst[i];
            atomicAdd(&h[d.x >> BSH], 1);
            atomicAdd(&h[d.y >> BSH], 1);
            atomicAdd(&h[d.z >> BSH], 1);
            atomicAdd(&h[d.w >> BSH], 1);
        }
        if (tid < (end - beg) - nfull)
            atomicAdd(&h[dst[beg + nfull + tid] >> BSH], 1);
    }
    __syncthreads();
    for (int c = tid; c < NBC; c += TPB) OFS[c * EBLKS + b] = h[c];
}

// scanA: per-block sums (1024 elems/block) of OFS
__global__ __launch_bounds__(TPB)
void k_scanA(const int* __restrict__ OFS, int* __restrict__ bsum, int total) {
    __shared__ int s[TPB];
    int tid = threadIdx.x;
    int i0  = blockIdx.x * 1024 + tid * 4;
    int t = 0;
#pragma unroll
    for (int k = 0; k < 4; ++k) {
        int i = i0 + k;
        t += (i < total) ? OFS[i] : 0;
    }
    s[tid] = t;
    __syncthreads();
    for (int off = TPB / 2; off > 0; off >>= 1) {
        if (tid < off) s[tid] += s[tid + off];
        __syncthreads();
    }
    if (tid == 0) bsum[blockIdx.x] = s[0];
}

// scanC: exclusive scan; each block computes its own prefix over bsum
// via a masked 64-lane reduction (NBLK <= 64 here).
__global__ __launch_bounds__(TPB)
void k_scanC(int* __restrict__ OFS, const int* __restrict__ bsum,
             int NBLK, int total) {
    __shared__ int s[TPB];
    __shared__ int pfx;
    int tid = threadIdx.x;
    if (tid < 64) {
        int v = (tid < NBLK && tid < (int)blockIdx.x) ? bsum[tid] : 0;
#pragma unroll
        for (int off = 1; off < 64; off <<= 1) v += __shfl_xor(v, off);
        if (tid == 0) pfx = v;
    }
    int i0 = blockIdx.x * 1024 + tid * 4;
    int v[4];
#pragma unroll
    for (int k = 0; k < 4; ++k) {
        int i = i0 + k;
        v[k] = (i < total) ? OFS[i] : 0;
    }
    int tsum = v[0] + v[1] + v[2] + v[3];
    s[tid] = tsum;
    __syncthreads();
    for (int off = 1; off < TPB; off <<= 1) {
        int x = (tid >= off) ? s[tid - off] : 0;
        __syncthreads();
        s[tid] += x;
        __syncthreads();
    }
    int base = pfx + (s[tid] - tsum);
#pragma unroll
    for (int k = 0; k < 4; ++k) {
        int i = i0 + k;
        if (i < total) {
            OFS[i] = base;
            base += v[k];
        }
    }
}

// P1c: scatter packed (src<<9|local) into bucket-contiguous ebuf (LDS cursors)
__global__ __launch_bounds__(TPB)
void k_p1scatter(const int* __restrict__ src, const int* __restrict__ dst,
                 const int* __restrict__ OFS, int* __restrict__ ebuf,
                 int E, int CH, int NBC) {
    __shared__ int cur[512];
    int tid = threadIdx.x, b = blockIdx.x;
    for (int c = tid; c < NBC; c += TPB) cur[c] = OFS[c * EBLKS + b];
    __syncthreads();
    int beg = b * CH, end = min(E, beg + CH);
    if (beg >= end) return;
    int nfull = (end - beg) & ~3;
    for (int i = beg + tid * 4; i < beg + nfull; i += TPB * 4) {
        int4 s4 = *(const int4*)&src[i];
        int4 d4 = *(const int4*)&dst[i];
        int p0 = atomicAdd(&cur[d4.x >> BSH], 1);
        int p1 = atomicAdd(&cur[d4.y >> BSH], 1);
        int p2 = atomicAdd(&cur[d4.z >> BSH], 1);
        int p3 = atomicAdd(&cur[d4.w >> BSH], 1);
        ebuf[p0] = (s4.x << BSH) | (d4.x & (BNODES - 1));
        ebuf[p1] = (s4.y << BSH) | (d4.y & (BNODES - 1));
        ebuf[p2] = (s4.z << BSH) | (d4.z & (BNODES - 1));
        ebuf[p3] = (s4.w << BSH) | (d4.w & (BNODES - 1));
    }
    if (tid < (end - beg) - nfull) {
        int i = beg + nfull + tid;
        int d = dst[i];
        int p = atomicAdd(&cur[d >> BSH], 1);
        ebuf[p] = (src[i] << BSH) | (d & (BNODES - 1));
    }
}

// P2 (fused): per bucket: LDS hist over 512 local nodes -> scan ->
// row_ptr/dinv + LDS start offsets; degree-binned counting sort -> perm;
// then rank pass -> colw[ofs+rank] = src.
__global__ __launch_bounds__(TPB)
void k_p2(const int* __restrict__ ebuf, const int* __restrict__ OFS,
          int* __restrict__ row_ptr, float* __restrict__ dinv,
          int* __restrict__ colw, int* __restrict__ perm,
          int N, int E, int NBC) {
    __shared__ int cnt[BNODES];
    __shared__ int ofs[BNODES];
    __shared__ int s1[TPB];
    __shared__ int dh[64];   // degree histogram (clamped bins)
    __shared__ int db[64];   // degree base / cursor
    int tid = threadIdx.x, c = blockIdx.x;
    int beg = OFS[c * EBLKS];
    int end = (c == NBC - 1) ? E : OFS[(c + 1) * EBLKS];
    for (int i = tid; i < BNODES; i += TPB) cnt[i] = 0;
    __syncthreads();
    for (int i = beg + tid; i < end; i += TPB)
        atomicAdd(&cnt[ebuf[i] & (BNODES - 1)], 1);
    __syncthreads();
    int a0 = cnt[2 * tid], a1 = cnt[2 * tid + 1];
    int pairsum = a0 + a1;
    s1[tid] = pairsum;
    __syncthreads();
    for (int off = 1; off < TPB; off <<= 1) {
        int x = (tid >= off) ? s1[tid - off] : 0;
        __syncthreads();
        s1[tid] += x;
        __syncthreads();
    }
    int ex = s1[tid] - pairsum;
    int cbase = c << BSH;
    int node0 = cbase + 2 * tid;
    bool has0 = node0 < N, has1 = node0 + 1 < N;
    ofs[2 * tid]     = beg + ex;
    ofs[2 * tid + 1] = beg + ex + a0;
    if (has0) {
        row_ptr[node0] = beg + ex;
        dinv[node0]    = rsqrtf((float)(a0 + 1));
    }
    if (has1) {
        row_ptr[node0 + 1] = beg + ex + a0;
        dinv[node0 + 1]    = rsqrtf((float)(a1 + 1));
    }
    if (c == NBC - 1 && tid == 0) row_ptr[N] = E;

    // --- degree-binned counting sort of this bucket's nodes -> perm ---
    if (tid < 64) dh[tid] = 0;
    cnt[2 * tid] = 0;            // reset for the rank/fill pass below
    cnt[2 * tid + 1] = 0;
    __syncthreads();
    int b0 = min(a0, 63), b1 = min(a1, 63);
    if (has0) atomicAdd(&dh[b0], 1);
    if (has1) atomicAdd(&dh[b1], 1);
    __syncthreads();
    if (tid < 64) {
        int v = dh[tid];
        int incl = v;
#pragma unroll
        for (int o = 1; o < 64; o <<= 1) {
            int x = __shfl_up(incl, o);
            if ((tid & 63) >= o) incl += x;
        }
        db[tid] = incl - v;      // exclusive base -> cursor
    }
    __syncthreads();
    if (has0) { int r = atomicAdd(&db[b0], 1); perm[cbase + r] = node0; }
    if (has1) { int r = atomicAdd(&db[b1], 1); perm[cbase + r] = node0 + 1; }

    // --- rank + fill (colw = src only) ---
    for (int i0 = beg + tid; i0 < end; i0 += TPB * 4) {
        int sv[4], dl[4], pos[4];
        int have = 0;
#pragma unroll
        for (int k = 0; k < 4; ++k) {
            int i = i0 + k * TPB;
            if (i < end) {
                int e = ebuf[i];
                sv[k] = e >> BSH;
                dl[k] = e & (BNODES - 1);
                have = k + 1;
            }
        }
#pragma unroll
        for (int k = 0; k < 4; ++k) {
            if (k < have) {
                int r  = atomicAdd(&cnt[dl[k]], 1);
                pos[k] = ofs[dl[k]] + r;
            }
        }
#pragma unroll
        for (int k = 0; k < 4; ++k)
            if (k < have) colw[pos[k]] = sv[k];
    }
}

// Dense GEMM: [n,64] @ [64,F].
// !FINAL: out = fp16 t' = dinv[row]*(row@W); also writes zero sentinel row n.
// FINAL:  out = fp32 row@W + bias.
// HIN: input rows fp16, else fp32.
template <int F, bool FINAL, bool HIN>
__launch_bounds__(256)
__global__ void k_mm(const void* __restrict__ in, const float* __restrict__ W,
                     const float* __restrict__ bias, const float* __restrict__ dinv,
                     void* __restrict__ out, int n) {
    __shared__ float in_s[64 * 68];
    __shared__ float w_s[64 * F];

    const int tid  = threadIdx.x;
    const int row0 = blockIdx.x * 64;

    for (int i4 = tid; i4 < (64 * F) / 4; i4 += 256)
        ((float4*)w_s)[i4] = ((const float4*)W)[i4];

    if constexpr (HIN) {
        for (int idx = tid; idx < 64 * 8; idx += 256) {
            int r  = idx >> 3;
            int c8 = idx & 7;
            uint4 u = make_uint4(0u, 0u, 0u, 0u);
            if (row0 + r < n)
                u = *(const uint4*)((const __half*)in + (size_t)(row0 + r) * 64 + c8 * 8);
            float2 f0 = __half22float2(*(__half2*)&u.x);
            float2 f1 = __half22float2(*(__half2*)&u.y);
            float2 f2 = __half22float2(*(__half2*)&u.z);
            float2 f3 = __half22float2(*(__half2*)&u.w);
            float* o = &in_s[r * 68 + c8 * 8];
            *(float4*)&o[0] = make_float4(f0.x, f0.y, f1.x, f1.y);
            *(float4*)&o[4] = make_float4(f2.x, f2.y, f3.x, f3.y);
        }
    } else {
        for (int idx = tid; idx < 64 * 16; idx += 256) {
            int r  = idx >> 4;
            int c4 = idx & 15;
            float4 v;
            if (row0 + r < n)
                v = *(const float4*)((const float*)in + (size_t)(row0 + r) * 64 + c4 * 4);
            else
                v = make_float4(0.f, 0.f, 0.f, 0.f);
            *(float4*)&in_s[r * 68 + c4 * 4] = v;
        }
    }
    __syncthreads();

    constexpr int CPT = F / 16;
    const int tx = tid & 15;
    const int ty = tid >> 4;

    float acc[4][CPT];
#pragma unroll
    for (int r = 0; r < 4; ++r)
#pragma unroll
        for (int c = 0; c < CPT; ++c) acc[r][c] = 0.f;

#pragma unroll 4
    for (int k = 0; k < 64; ++k) {
        float b[CPT];
#pragma unroll
        for (int c = 0; c < CPT; ++c) b[c] = w_s[k * F + tx * CPT + c];
#pragma unroll
        for (int r = 0; r < 4; ++r) {
            float a = in_s[(ty * 4 + r) * 68 + k];
#pragma unroll
            for (int c = 0; c < CPT; ++c) acc[r][c] = fmaf(a, b[c], acc[r][c]);
        }
    }

#pragma unroll
    for (int r = 0; r < 4; ++r) {
        int row = row0 + ty * 4 + r;
        if (row >= n) continue;
        if constexpr (FINAL) {
#pragma unroll
            for (int c = 0; c < CPT; ++c) {
                int col = tx * CPT + c;
                ((float*)out)[(size_t)row * F + col] = acc[r][c] + bias[col];
            }
        } else {
            float dd = dinv[row];
            __half2 p0 = __floats2half2_rn(acc[r][0] * dd, acc[r][1] * dd);
            __half2 p1 = __floats2half2_rn(acc[r][2] * dd, acc[r][3] * dd);
            uint2 u = make_uint2(*(unsigned*)&p0, *(unsigned*)&p1);
            *(uint2*)((__half*)out + (size_t)row * 64 + tx * 4) = u;
        }
    }
    if constexpr (!FINAL) {
        // zero sentinel row n (tail edges in gather read it)
        if (blockIdx.x == 0 && tid < 16)
            *(uint2*)((__half*)out + (size_t)n * 64 + tid * 4) = make_uint2(0u, 0u);
    }
}

// Gather: 8 nodes/wave (degree-sorted via perm -> uniform loop lengths),
// 8 lanes/node, edge loop unrolled x4, no weights (t' pre-scaled):
// agg[d] = relu(bias + dinv[d] * (sum_e t'[src_e] + t'[d])), fp16 out.
__global__ __launch_bounds__(256)
void k_gather(const int* __restrict__ row_ptr, const int* __restrict__ colw,
              const int* __restrict__ perm,
              const float* __restrict__ dinv, const float* __restrict__ bias,
              const __half* __restrict__ t, __half* __restrict__ agg, int N) {
    int tid  = threadIdx.x;
    int wv   = tid >> 6;
    int lane = tid & 63;
    int g = lane >> 3;
    int p = lane & 7;
    int idx = blockIdx.x * 32 + wv * 8 + g;

    int d = 0, beg = 0, end = 0;
    if (idx < N) {
        d   = perm[idx];
        beg = row_ptr[d];
        end = row_ptr[d + 1];
    }

    float acc[8];
#pragma unroll
    for (int k = 0; k < 8; ++k) acc[k] = 0.f;

    for (int e = beg; e < end; e += 4) {
        int s0 = colw[e];
        int s1 = (e + 1 < end) ? colw[e + 1] : N;   // N = zero sentinel row
        int s2 = (e + 2 < end) ? colw[e + 2] : N;
        int s3 = (e + 3 < end) ? colw[e + 3] : N;
        uint4 a0 = *(const uint4*)(t + (size_t)s0 * 64 + p * 8);
        uint4 a1 = *(const uint4*)(t + (size_t)s1 * 64 + p * 8);
        uint4 a2 = *(const uint4*)(t + (size_t)s2 * 64 + p * 8);
        uint4 a3 = *(const uint4*)(t + (size_t)s3 * 64 + p * 8);
        float2 f;
        f = __half22float2(*(__half2*)&a0.x); acc[0] += f.x; acc[1] += f.y;
        f = __half22float2(*(__half2*)&a0.y); acc[2] += f.x; acc[3] += f.y;
        f = __half22float2(*(__half2*)&a0.z); acc[4] += f.x; acc[5] += f.y;
        f = __half22float2(*(__half2*)&a0.w); acc[6] += f.x; acc[7] += f.y;
        f = __half22float2(*(__half2*)&a1.x); acc[0] += f.x; acc[1] += f.y;
        f = __half22float2(*(__half2*)&a1.y); acc[2] += f.x; acc[3] += f.y;
        f = __half22float2(*(__half2*)&a1.z); acc[4] += f.x; acc[5] += f.y;
        f = __half22float2(*(__half2*)&a1.w); acc[6] += f.x; acc[7] += f.y;
        f = __half22float2(*(__half2*)&a2.x); acc[0] += f.x; acc[1] += f.y;
        f = __half22float2(*(__half2*)&a2.y); acc[2] += f.x; acc[3] += f.y;
        f = __half22float2(*(__half2*)&a2.z); acc[4] += f.x; acc[5] += f.y;
        f = __half22float2(*(__half2*)&a2.w); acc[6] += f.x; acc[7] += f.y;
        f = __half22float2(*(__half2*)&a3.x); acc[0] += f.x; acc[1] += f.y;
        f = __half22float2(*(__half2*)&a3.y); acc[2] += f.x; acc[3] += f.y;
        f = __half22float2(*(__half2*)&a3.z); acc[4] += f.x; acc[5] += f.y;
        f = __half22float2(*(__half2*)&a3.w); acc[6] += f.x; acc[7] += f.y;
    }

    if (idx < N) {
        float dd = dinv[d];
        uint4 a = *(const uint4*)(t + (size_t)d * 64 + p * 8);
        float4 b0 = *(const float4*)&bias[p * 8];
        float4 b1 = *(const float4*)&bias[p * 8 + 4];
        float2 s0 = __half22float2(*(__half2*)&a.x);
        float2 s1 = __half22float2(*(__half2*)&a.y);
        float2 s2 = __half22float2(*(__half2*)&a.z);
        float2 s3 = __half22float2(*(__half2*)&a.w);
        float o0 = fmaxf(fmaf(dd, acc[0] + s0.x, b0.x), 0.f);
        float o1 = fmaxf(fmaf(dd, acc[1] + s0.y, b0.y), 0.f);
        float o2 = fmaxf(fmaf(dd, acc[2] + s1.x, b0.z), 0.f);
        float o3 = fmaxf(fmaf(dd, acc[3] + s1.y, b0.w), 0.f);
        float o4 = fmaxf(fmaf(dd, acc[4] + s2.x, b1.x), 0.f);
        float o5 = fmaxf(fmaf(dd, acc[5] + s2.y, b1.y), 0.f);
        float o6 = fmaxf(fmaf(dd, acc[6] + s3.x, b1.z), 0.f);
        float o7 = fmaxf(fmaf(dd, acc[7] + s3.y, b1.w), 0.f);
        __half2 h0 = __floats2half2_rn(o0, o1);
        __half2 h1 = __floats2half2_rn(o2, o3);
        __half2 h2 = __floats2half2_rn(o4, o5);
        __half2 h3 = __floats2half2_rn(o6, o7);
        uint4 u = make_uint4(*(unsigned*)&h0, *(unsigned*)&h1,
                             *(unsigned*)&h2, *(unsigned*)&h3);
        *(uint4*)(agg + (size_t)d * 64 + p * 8) = u;
    }
}

extern "C" void kernel_launch(void* const* d_in, const int* in_sizes, int n_in,
                              void* d_out, int out_size, void* d_ws, size_t ws_size,
                              hipStream_t stream) {
    const float* x  = (const float*)d_in[0];
    const int*   ei = (const int*)d_in[1];
    const float* W1 = (const float*)d_in[2];
    const float* b1 = (const float*)d_in[3];
    const float* W2 = (const float*)d_in[4];
    const float* b2 = (const float*)d_in[5];
    const float* Wl = (const float*)d_in[6];
    const float* bl = (const float*)d_in[7];
    float*       out = (float*)d_out;

    const int N = in_sizes[0] / 64;
    const int E = in_sizes[1] / 2;
    const int* srcp = ei;
    const int* dstp = ei + E;

    const int NBC   = (N + BNODES - 1) / BNODES;             // buckets
    const int CH    = (((E + EBLKS - 1) / EBLKS) + 3) & ~3;  // chunk, mult of 4
    const int total = NBC * EBLKS;                           // offset matrix
    const int NBLK  = (total + 1023) / 1024;                 // scan blocks (<=64)

    char*  ws  = (char*)d_ws;
    size_t off = 0;
    auto alloc = [&](size_t bytes) -> void* {
        void* p = (void*)(ws + off);
        off += (bytes + 255) & ~(size_t)255;
        return p;
    };
    int*    OFS     = (int*)alloc(((size_t)total + 1) * 4);
    int*    bsum    = (int*)alloc((size_t)NBLK * 4);
    int*    ebuf    = (int*)alloc((size_t)E * 4);
    int*    row_ptr = (int*)alloc((size_t)(N + 1) * 4);
    float*  dinv    = (float*)alloc((size_t)N * 4);
    int*    colw    = (int*)alloc((size_t)E * 4);
    int*    perm    = (int*)alloc((size_t)N * 4);
    __half* t1      = (__half*)alloc((size_t)(N + 1) * 64 * 2);  // +sentinel
    __half* agg1    = (__half*)alloc((size_t)N * 64 * 2);
    __half* t2      = t1;    // safe: t1 dead once gather1 consumed it
    __half* agg2    = agg1;  // safe: agg1 dead once mm2 wrote t2

    const int nb_mm = (N + 63) / 64;
    const int nb_g  = (N + 31) / 32;

    // --- CSR build (no global atomics) ---
    k_p1hist   <<<EBLKS, TPB, 0, stream>>>(dstp, OFS, E, CH, NBC);
    k_scanA    <<<NBLK,  TPB, 0, stream>>>(OFS, bsum, total);
    k_scanC    <<<NBLK,  TPB, 0, stream>>>(OFS, bsum, NBLK, total);
    k_p1scatter<<<EBLKS, TPB, 0, stream>>>(srcp, dstp, OFS, ebuf, E, CH, NBC);
    k_p2       <<<NBC,   TPB, 0, stream>>>(ebuf, OFS, row_ptr, dinv, colw, perm, N, E, NBC);

    // --- layer 1: t1' = dinv * (x @ W1) ---
    k_mm<64, false, false><<<nb_mm, 256, 0, stream>>>(x, W1, nullptr, dinv, t1, N);
    k_gather<<<nb_g, 256, 0, stream>>>(row_ptr, colw, perm, dinv, b1, t1, agg1, N);

    // --- layer 2: t2' = dinv * (agg1 @ W2) ---
    k_mm<64, false, true><<<nb_mm, 256, 0, stream>>>(agg1, W2, nullptr, dinv, t2, N);
    k_gather<<<nb_g, 256, 0, stream>>>(row_ptr, colw, perm, dinv, b2, t2, agg2, N);

    // --- head ---
    k_mm<32, true, true><<<nb_mm, 256, 0, stream>>>(agg2, Wl, bl, nullptr, out, N);
}

// Round 13
// 201.076 us; speedup vs baseline: 1.0881x; 1.0881x over previous
//
#include <hip/hip_runtime.h>
#include <hip/hip_fp16.h>
#include <math.h>

// ---------------------------------------------------------------------------
// GCN. CSR build = bucketed counting sort, LDS atomics only (no global
// atomics: device-scope atomic-returns run memory-side at ~23 Gops/s on
// multi-XCD CDNA4 — measured R3/R4). ebuf packed (src<<7|local) in 4 B.
// t' = dinv[row] * (row @ W) (scaled in mm epilogue) so
//   agg[d] = relu(b + dinv[d] * (sum_e t'[src_e] + t'[d]))
// colw stores ONLY src (4 B); gather inner loop is pure adds.
// R13: occupancy fix for the CSR build (measured ~105 us, half the total):
//   p1 kernels at TPB=1024 (16 waves/CU, was 4); buckets shrunk to 128
//   nodes (BSH=7) so p2 runs 782 blocks (~3/CU, was <1/CU).
// R12's degree-perm REVERTED (scattered agg writes cost more than the
// divergence it saved). R10's gather-GEMM fusion REVERTED (occupancy).
// ---------------------------------------------------------------------------

#define TPB    256
#define TPB1   1024         // pass-1 block size (occupancy)
#define EBLKS  256          // pass-1 edge blocks
#define BSH    7            // 128 nodes per bucket
#define BNODES (1 << BSH)

// P1a: OFS[c*EBLKS + b] = #edges of bucket c in block b's chunk
__global__ __launch_bounds__(TPB1)
void k_p1hist(const int* __restrict__ dst, int* __restrict__ OFS,
              int E, int CH, int NBC) {
    __shared__ int h[1024];
    int tid = threadIdx.x, b = blockIdx.x;
    h[tid] = 0;
    __syncthreads();
    int beg = b * CH, end = min(E, beg + CH);
    if (beg < end) {
        int nfull = (end - beg) & ~3;
        for (int i = beg + tid * 4; i < beg + nfull; i += TPB1 * 4) {
            int4 d = *(const int4*)&dst[i];
            atomicAdd(&h[d.x >> BSH], 1);
            atomicAdd(&h[d.y >> BSH], 1);
            atomicAdd(&h[d.z >> BSH], 1);
            atomicAdd(&h[d.w >> BSH], 1);
        }
        if (tid < (end - beg) - nfull)
            atomicAdd(&h[dst[beg + nfull + tid] >> BSH], 1);
    }
    __syncthreads();
    for (int c = tid; c < NBC; c += TPB1) OFS[c * EBLKS + b] = h[c];
}

// scanA: per-block sums (1024 elems/block) of OFS
__global__ __launch_bounds__(TPB)
void k_scanA(const int* __restrict__ OFS, int* __restrict__ bsum, int total) {
    __shared__ int s[TPB];
    int tid = threadIdx.x;
    int i0  = blockIdx.x * 1024 + tid * 4;
    int t = 0;
#pragma unroll
    for (int k = 0; k < 4; ++k) {
        int i = i0 + k;
        t += (i < total) ? OFS[i] : 0;
    }
    s[tid] = t;
    __syncthreads();
    for (int off = TPB / 2; off > 0; off >>= 1) {
        if (tid < off) s[tid] += s[tid + off];
        __syncthreads();
    }
    if (tid == 0) bsum[blockIdx.x] = s[0];
}

// scanC: exclusive scan; each block sums bsum[0..blockIdx) via a looped
// 64-lane reduction (works for any NBLK).
__global__ __launch_bounds__(TPB)
void k_scanC(int* __restrict__ OFS, const int* __restrict__ bsum, int total) {
    __shared__ int s[TPB];
    __shared__ int pfx;
    int tid = threadIdx.x;
    if (tid < 64) {
        int v = 0;
        for (int j = tid; j < (int)blockIdx.x; j += 64) v += bsum[j];
#pragma unroll
        for (int off = 1; off < 64; off <<= 1) v += __shfl_xor(v, off);
        if (tid == 0) pfx = v;
    }
    int i0 = blockIdx.x * 1024 + tid * 4;
    int v[4];
#pragma unroll
    for (int k = 0; k < 4; ++k) {
        int i = i0 + k;
        v[k] = (i < total) ? OFS[i] : 0;
    }
    int tsum = v[0] + v[1] + v[2] + v[3];
    s[tid] = tsum;
    __syncthreads();
    for (int off = 1; off < TPB; off <<= 1) {
        int x = (tid >= off) ? s[tid - off] : 0;
        __syncthreads();
        s[tid] += x;
        __syncthreads();
    }
    int base = pfx + (s[tid] - tsum);
#pragma unroll
    for (int k = 0; k < 4; ++k) {
        int i = i0 + k;
        if (i < total) {
            OFS[i] = base;
            base += v[k];
        }
    }
}

// P1c: scatter packed (src<<7|local) into bucket-contiguous ebuf (LDS cursors)
__global__ __launch_bounds__(TPB1)
void k_p1scatter(const int* __restrict__ src, const int* __restrict__ dst,
                 const int* __restrict__ OFS, int* __restrict__ ebuf,
                 int E, int CH, int NBC) {
    __shared__ int cur[1024];
    int tid = threadIdx.x, b = blockIdx.x;
    for (int c = tid; c < NBC; c += TPB1) cur[c] = OFS[c * EBLKS + b];
    __syncthreads();
    int beg = b * CH, end = min(E, beg + CH);
    if (beg >= end) return;
    int nfull = (end - beg) & ~3;
    for (int i = beg + tid * 4; i < beg + nfull; i += TPB1 * 4) {
        int4 s4 = *(const int4*)&src[i];
        int4 d4 = *(const int4*)&dst[i];
        int p0 = atomicAdd(&cur[d4.x >> BSH], 1);
        int p1 = atomicAdd(&cur[d4.y >> BSH], 1);
        int p2 = atomicAdd(&cur[d4.z >> BSH], 1);
        int p3 = atomicAdd(&cur[d4.w >> BSH], 1);
        ebuf[p0] = (s4.x << BSH) | (d4.x & (BNODES - 1));
        ebuf[p1] = (s4.y << BSH) | (d4.y & (BNODES - 1));
        ebuf[p2] = (s4.z << BSH) | (d4.z & (BNODES - 1));
        ebuf[p3] = (s4.w << BSH) | (d4.w & (BNODES - 1));
    }
    if (tid < (end - beg) - nfull) {
        int i = beg + nfull + tid;
        int d = dst[i];
        int p = atomicAdd(&cur[d >> BSH], 1);
        ebuf[p] = (src[i] << BSH) | (d & (BNODES - 1));
    }
}

// P2 (fused): per 128-node bucket: LDS hist -> scan -> row_ptr/dinv + LDS
// start offsets; then rank pass -> colw[ofs+rank] = src.
__global__ __launch_bounds__(TPB)
void k_p2(const int* __restrict__ ebuf, const int* __restrict__ OFS,
          int* __restrict__ row_ptr, float* __restrict__ dinv,
          int* __restrict__ colw, int N, int E, int NBC) {
    __shared__ int cnt[BNODES];
    __shared__ int ofs[BNODES];
    __shared__ int s1[TPB];
    int tid = threadIdx.x, c = blockIdx.x;
    int beg = OFS[c * EBLKS];
    int end = (c == NBC - 1) ? E : OFS[(c + 1) * EBLKS];
    if (tid < BNODES) cnt[tid] = 0;
    __syncthreads();
    for (int i = beg + tid; i < end; i += TPB)
        atomicAdd(&cnt[ebuf[i] & (BNODES - 1)], 1);
    __syncthreads();
    int a = (tid < BNODES) ? cnt[tid] : 0;
    s1[tid] = a;
    __syncthreads();
    for (int off = 1; off < TPB; off <<= 1) {
        int x = (tid >= off) ? s1[tid - off] : 0;
        __syncthreads();
        s1[tid] += x;
        __syncthreads();
    }
    int ex = s1[tid] - a;   // exclusive
    if (tid < BNODES) {
        int node = (c << BSH) + tid;
        ofs[tid] = beg + ex;
        if (node < N) {
            row_ptr[node] = beg + ex;
            dinv[node]    = rsqrtf((float)(a + 1));
        }
        cnt[tid] = 0;       // reset for rank pass
    }
    if (c == NBC - 1 && tid == 0) row_ptr[N] = E;
    __syncthreads();
    // rank + fill (colw = src only)
    for (int i0 = beg + tid; i0 < end; i0 += TPB * 4) {
        int sv[4], dl[4], pos[4];
        int have = 0;
#pragma unroll
        for (int k = 0; k < 4; ++k) {
            int i = i0 + k * TPB;
            if (i < end) {
                int e = ebuf[i];
                sv[k] = e >> BSH;
                dl[k] = e & (BNODES - 1);
                have = k + 1;
            }
        }
#pragma unroll
        for (int k = 0; k < 4; ++k) {
            if (k < have) {
                int r  = atomicAdd(&cnt[dl[k]], 1);
                pos[k] = ofs[dl[k]] + r;
            }
        }
#pragma unroll
        for (int k = 0; k < 4; ++k)
            if (k < have) colw[pos[k]] = sv[k];
    }
}

// Dense GEMM: [n,64] @ [64,F].
// !FINAL: out = fp16 t' = dinv[row]*(row@W); also writes zero sentinel row n.
// FINAL:  out = fp32 row@W + bias.
// HIN: input rows fp16, else fp32.
template <int F, bool FINAL, bool HIN>
__launch_bounds__(256)
__global__ void k_mm(const void* __restrict__ in, const float* __restrict__ W,
                     const float* __restrict__ bias, const float* __restrict__ dinv,
                     void* __restrict__ out, int n) {
    __shared__ float in_s[64 * 68];
    __shared__ float w_s[64 * F];

    const int tid  = threadIdx.x;
    const int row0 = blockIdx.x * 64;

    for (int i4 = tid; i4 < (64 * F) / 4; i4 += 256)
        ((float4*)w_s)[i4] = ((const float4*)W)[i4];

    if constexpr (HIN) {
        for (int idx = tid; idx < 64 * 8; idx += 256) {
            int r  = idx >> 3;
            int c8 = idx & 7;
            uint4 u = make_uint4(0u, 0u, 0u, 0u);
            if (row0 + r < n)
                u = *(const uint4*)((const __half*)in + (size_t)(row0 + r) * 64 + c8 * 8);
            float2 f0 = __half22float2(*(__half2*)&u.x);
            float2 f1 = __half22float2(*(__half2*)&u.y);
            float2 f2 = __half22float2(*(__half2*)&u.z);
            float2 f3 = __half22float2(*(__half2*)&u.w);
            float* o = &in_s[r * 68 + c8 * 8];
            *(float4*)&o[0] = make_float4(f0.x, f0.y, f1.x, f1.y);
            *(float4*)&o[4] = make_float4(f2.x, f2.y, f3.x, f3.y);
        }
    } else {
        for (int idx = tid; idx < 64 * 16; idx += 256) {
            int r  = idx >> 4;
            int c4 = idx & 15;
            float4 v;
            if (row0 + r < n)
                v = *(const float4*)((const float*)in + (size_t)(row0 + r) * 64 + c4 * 4);
            else
                v = make_float4(0.f, 0.f, 0.f, 0.f);
            *(float4*)&in_s[r * 68 + c4 * 4] = v;
        }
    }
    __syncthreads();

    constexpr int CPT = F / 16;
    const int tx = tid & 15;
    const int ty = tid >> 4;

    float acc[4][CPT];
#pragma unroll
    for (int r = 0; r < 4; ++r)
#pragma unroll
        for (int c = 0; c < CPT; ++c) acc[r][c] = 0.f;

#pragma unroll 4
    for (int k = 0; k < 64; ++k) {
        float b[CPT];
#pragma unroll
        for (int c = 0; c < CPT; ++c) b[c] = w_s[k * F + tx * CPT + c];
#pragma unroll
        for (int r = 0; r < 4; ++r) {
            float a = in_s[(ty * 4 + r) * 68 + k];
#pragma unroll
            for (int c = 0; c < CPT; ++c) acc[r][c] = fmaf(a, b[c], acc[r][c]);
        }
    }

#pragma unroll
    for (int r = 0; r < 4; ++r) {
        int row = row0 + ty * 4 + r;
        if (row >= n) continue;
        if constexpr (FINAL) {
#pragma unroll
            for (int c = 0; c < CPT; ++c) {
                int col = tx * CPT + c;
                ((float*)out)[(size_t)row * F + col] = acc[r][c] + bias[col];
            }
        } else {
            float dd = dinv[row];
            __half2 p0 = __floats2half2_rn(acc[r][0] * dd, acc[r][1] * dd);
            __half2 p1 = __floats2half2_rn(acc[r][2] * dd, acc[r][3] * dd);
            uint2 u = make_uint2(*(unsigned*)&p0, *(unsigned*)&p1);
            *(uint2*)((__half*)out + (size_t)row * 64 + tx * 4) = u;
        }
    }
    if constexpr (!FINAL) {
        // zero sentinel row n (tail edges in gather read it)
        if (blockIdx.x == 0 && tid < 16)
            *(uint2*)((__half*)out + (size_t)n * 64 + tid * 4) = make_uint2(0u, 0u);
    }
}

// Gather: 8 nodes/wave, 8 lanes/node, edge loop unrolled x4, no weights
// (t' pre-scaled): agg[d] = relu(bias + dinv[d]*(sum_e t'[src_e] + t'[d])).
__global__ __launch_bounds__(256)
void k_gather(const int* __restrict__ row_ptr, const int* __restrict__ colw,
              const float* __restrict__ dinv, const float* __restrict__ bias,
              const __half* __restrict__ t, __half* __restrict__ agg, int N) {
    int tid  = threadIdx.x;
    int wv   = tid >> 6;
    int lane = tid & 63;
    int g = lane >> 3;
    int p = lane & 7;
    int d = blockIdx.x * 32 + wv * 8 + g;

    int beg = 0, end = 0;
    if (d < N) { beg = row_ptr[d]; end = row_ptr[d + 1]; }

    float acc[8];
#pragma unroll
    for (int k = 0; k < 8; ++k) acc[k] = 0.f;

    for (int e = beg; e < end; e += 4) {
        int s0 = colw[e];
        int s1 = (e + 1 < end) ? colw[e + 1] : N;   // N = zero sentinel row
        int s2 = (e + 2 < end) ? colw[e + 2] : N;
        int s3 = (e + 3 < end) ? colw[e + 3] : N;
        uint4 a0 = *(const uint4*)(t + (size_t)s0 * 64 + p * 8);
        uint4 a1 = *(const uint4*)(t + (size_t)s1 * 64 + p * 8);
        uint4 a2 = *(const uint4*)(t + (size_t)s2 * 64 + p * 8);
        uint4 a3 = *(const uint4*)(t + (size_t)s3 * 64 + p * 8);
        float2 f;
        f = __half22float2(*(__half2*)&a0.x); acc[0] += f.x; acc[1] += f.y;
        f = __half22float2(*(__half2*)&a0.y); acc[2] += f.x; acc[3] += f.y;
        f = __half22float2(*(__half2*)&a0.z); acc[4] += f.x; acc[5] += f.y;
        f = __half22float2(*(__half2*)&a0.w); acc[6] += f.x; acc[7] += f.y;
        f = __half22float2(*(__half2*)&a1.x); acc[0] += f.x; acc[1] += f.y;
        f = __half22float2(*(__half2*)&a1.y); acc[2] += f.x; acc[3] += f.y;
        f = __half22float2(*(__half2*)&a1.z); acc[4] += f.x; acc[5] += f.y;
        f = __half22float2(*(__half2*)&a1.w); acc[6] += f.x; acc[7] += f.y;
        f = __half22float2(*(__half2*)&a2.x); acc[0] += f.x; acc[1] += f.y;
        f = __half22float2(*(__half2*)&a2.y); acc[2] += f.x; acc[3] += f.y;
        f = __half22float2(*(__half2*)&a2.z); acc[4] += f.x; acc[5] += f.y;
        f = __half22float2(*(__half2*)&a2.w); acc[6] += f.x; acc[7] += f.y;
        f = __half22float2(*(__half2*)&a3.x); acc[0] += f.x; acc[1] += f.y;
        f = __half22float2(*(__half2*)&a3.y); acc[2] += f.x; acc[3] += f.y;
        f = __half22float2(*(__half2*)&a3.z); acc[4] += f.x; acc[5] += f.y;
        f = __half22float2(*(__half2*)&a3.w); acc[6] += f.x; acc[7] += f.y;
    }

    if (d < N) {
        float dd = dinv[d];
        uint4 a = *(const uint4*)(t + (size_t)d * 64 + p * 8);
        float4 b0 = *(const float4*)&bias[p * 8];
        float4 b1 = *(const float4*)&bias[p * 8 + 4];
        float2 s0 = __half22float2(*(__half2*)&a.x);
        float2 s1 = __half22float2(*(__half2*)&a.y);
        float2 s2 = __half22float2(*(__half2*)&a.z);
        float2 s3 = __half22float2(*(__half2*)&a.w);
        float o0 = fmaxf(fmaf(dd, acc[0] + s0.x, b0.x), 0.f);
        float o1 = fmaxf(fmaf(dd, acc[1] + s0.y, b0.y), 0.f);
        float o2 = fmaxf(fmaf(dd, acc[2] + s1.x, b0.z), 0.f);
        float o3 = fmaxf(fmaf(dd, acc[3] + s1.y, b0.w), 0.f);
        float o4 = fmaxf(fmaf(dd, acc[4] + s2.x, b1.x), 0.f);
        float o5 = fmaxf(fmaf(dd, acc[5] + s2.y, b1.y), 0.f);
        float o6 = fmaxf(fmaf(dd, acc[6] + s3.x, b1.z), 0.f);
        float o7 = fmaxf(fmaf(dd, acc[7] + s3.y, b1.w), 0.f);
        __half2 h0 = __floats2half2_rn(o0, o1);
        __half2 h1 = __floats2half2_rn(o2, o3);
        __half2 h2 = __floats2half2_rn(o4, o5);
        __half2 h3 = __floats2half2_rn(o6, o7);
        uint4 u = make_uint4(*(unsigned*)&h0, *(unsigned*)&h1,
                             *(unsigned*)&h2, *(unsigned*)&h3);
        *(uint4*)(agg + (size_t)d * 64 + p * 8) = u;
    }
}

extern "C" void kernel_launch(void* const* d_in, const int* in_sizes, int n_in,
                              void* d_out, int out_size, void* d_ws, size_t ws_size,
                              hipStream_t stream) {
    const float* x  = (const float*)d_in[0];
    const int*   ei = (const int*)d_in[1];
    const float* W1 = (const float*)d_in[2];
    const float* b1 = (const float*)d_in[3];
    const float* W2 = (const float*)d_in[4];
    const float* b2 = (const float*)d_in[5];
    const float* Wl = (const float*)d_in[6];
    const float* bl = (const float*)d_in[7];
    float*       out = (float*)d_out;

    const int N = in_sizes[0] / 64;
    const int E = in_sizes[1] / 2;
    const int* srcp = ei;
    const int* dstp = ei + E;

    const int NBC   = (N + BNODES - 1) / BNODES;             // buckets (782)
    const int CH    = (((E + EBLKS - 1) / EBLKS) + 3) & ~3;  // chunk, mult of 4
    const int total = NBC * EBLKS;                           // offset matrix
    const int NBLK  = (total + 1023) / 1024;                 // scan blocks

    char*  ws  = (char*)d_ws;
    size_t off = 0;
    auto alloc = [&](size_t bytes) -> void* {
        void* p = (void*)(ws + off);
        off += (bytes + 255) & ~(size_t)255;
        return p;
    };
    int*    OFS     = (int*)alloc(((size_t)total + 1) * 4);
    int*    bsum    = (int*)alloc((size_t)NBLK * 4);
    int*    ebuf    = (int*)alloc((size_t)E * 4);
    int*    row_ptr = (int*)alloc((size_t)(N + 1) * 4);
    float*  dinv    = (float*)alloc((size_t)N * 4);
    int*    colw    = (int*)alloc((size_t)E * 4);
    __half* t1      = (__half*)alloc((size_t)(N + 1) * 64 * 2);  // +sentinel
    __half* agg1    = (__half*)alloc((size_t)N * 64 * 2);
    __half* t2      = t1;    // safe: t1 dead once gather1 consumed it
    __half* agg2    = agg1;  // safe: agg1 dead once mm2 wrote t2

    const int nb_mm = (N + 63) / 64;
    const int nb_g  = (N + 31) / 32;

    // --- CSR build (no global atomics) ---
    k_p1hist   <<<EBLKS, TPB1, 0, stream>>>(dstp, OFS, E, CH, NBC);
    k_scanA    <<<NBLK,  TPB,  0, stream>>>(OFS, bsum, total);
    k_scanC    <<<NBLK,  TPB,  0, stream>>>(OFS, bsum, total);
    k_p1scatter<<<EBLKS, TPB1, 0, stream>>>(srcp, dstp, OFS, ebuf, E, CH, NBC);
    k_p2       <<<NBC,   TPB,  0, stream>>>(ebuf, OFS, row_ptr, dinv, colw, N, E, NBC);

    // --- layer 1: t1' = dinv * (x @ W1) ---
    k_mm<64, false, false><<<nb_mm, 256, 0, stream>>>(x, W1, nullptr, dinv, t1, N);
    k_gather<<<nb_g, 256, 0, stream>>>(row_ptr, colw, dinv, b1, t1, agg1, N);

    // --- layer 2: t2' = dinv * (agg1 @ W2) ---
    k_mm<64, false, true><<<nb_mm, 256, 0, stream>>>(agg1, W2, nullptr, dinv, t2, N);
    k_gather<<<nb_g, 256, 0, stream>>>(row_ptr, colw, dinv, b2, t2, agg2, N);

    // --- head ---
    k_mm<32, true, true><<<nb_mm, 256, 0, stream>>>(agg2, Wl, bl, nullptr, out, N);
}